// Round 17
// baseline (2889.266 us; speedup 1.0000x reference)
//
#include <hip/hip_runtime.h>
#include <hip/hip_bf16.h>
#include <math.h>

#define NB 16384
#define DD 64
#define HH 256
#define NSTEP 63
#define RB 32          // rows per block -> grid 512
#define NT 1024        // 16 waves -> 4 waves/SIMD (LDS pins 1 block/CU)

#define SYW 68         // u32 stride, packed 64-wide bufs (y, actor)
#define SHW 260        // u32 stride, packed 256-wide bufs (h1, h2)

// g_wb layout (ushort units) — prep identical to R15
#define O1H 0
#define O1L 16384
#define O2H 32768
#define O2L 98304
#define O3H 163840
#define O3L 180224
#define AM1H 196608
#define AM1L 200704
#define AM2H 204800
#define AM2L 208896
#define AM3H 212992
#define AM3L 217088
#define AS1H 221184
#define AS1L 225280
#define AS2H 229376
#define AS2L 233472
#define AS3H 237568
#define AS3L 241664
#define WB_SHORTS 245760

__device__ unsigned short g_wb[WB_SHORTS];   // cached device memory

typedef __attribute__((ext_vector_type(8))) short s8v;
typedef __attribute__((ext_vector_type(4))) float f4v;
typedef __attribute__((ext_vector_type(4))) unsigned int u4v;

#define MFMA(a, b, c) __builtin_amdgcn_mfma_f32_16x16x32_bf16((a), (b), (c), 0, 0, 0)
#define MM3(acc, ah, al, bh, bl)                                 \
    do {                                                         \
        acc = MFMA(ah, bh, acc);                                 \
        acc = MFMA(ah, bl, acc);                                 \
        acc = MFMA(al, bh, acc);                                 \
    } while (0)

__device__ __forceinline__ unsigned short f2b(float x) {
    return __builtin_bit_cast(unsigned short, (__bf16)x);
}
__device__ __forceinline__ float b2f(unsigned short u) {
    return __builtin_bit_cast(float, (unsigned int)u << 16);
}
__device__ __forceinline__ unsigned int packsplit(float x) {
    const unsigned int xb = __builtin_bit_cast(unsigned int, x);
    const unsigned int hb = xb & 0xFFFF0000u;
    const float lof = x - __builtin_bit_cast(float, hb);
    const unsigned int lb = __builtin_bit_cast(unsigned int, lof);
    return __builtin_amdgcn_perm(lb, hb, 0x07060302);
}
__device__ __forceinline__ float fast_tanh(float x) {
    float e = __expf(-2.0f * fabsf(x));
    float r = __fdividef(1.0f - e, 1.0f + e);
    return copysignf(r, x);
}
__device__ __forceinline__ float fast_softplus(float x) {
    return fmaxf(x, 0.0f) + __logf(1.0f + __expf(-fabsf(x)));
}
__device__ __forceinline__ float clean_f(float x) { return isfinite(x) ? x : 0.0f; }
__device__ __forceinline__ f4v splat4(float b) { f4v v = {b, b, b, b}; return v; }

__device__ __forceinline__ void ldsPK(const unsigned int* p, s8v* hi, s8v* lo) {
    const u4v q0 = *(const u4v*)p;
    const u4v q1 = *(const u4v*)(p + 4);
    union { unsigned int u[4]; s8v v; } H, L;
    H.u[0] = __builtin_amdgcn_perm(q0[1], q0[0], 0x05040100);
    L.u[0] = __builtin_amdgcn_perm(q0[1], q0[0], 0x07060302);
    H.u[1] = __builtin_amdgcn_perm(q0[3], q0[2], 0x05040100);
    L.u[1] = __builtin_amdgcn_perm(q0[3], q0[2], 0x07060302);
    H.u[2] = __builtin_amdgcn_perm(q1[1], q1[0], 0x05040100);
    L.u[2] = __builtin_amdgcn_perm(q1[1], q1[0], 0x07060302);
    H.u[3] = __builtin_amdgcn_perm(q1[3], q1[2], 0x05040100);
    L.u[3] = __builtin_amdgcn_perm(q1[3], q1[2], 0x07060302);
    *hi = H.v; *lo = L.v;
}

// async 16B/lane global->LDS
__device__ __forceinline__ void gld16(const unsigned short* g, unsigned int* l) {
    __builtin_amdgcn_global_load_lds(
        (const __attribute__((address_space(1))) void*)(g),
        (__attribute__((address_space(3))) void*)(l), 16, 0, 0);
}
__device__ __forceinline__ s8v ldw(const unsigned int* wb, int j, int l) {
    return *(const s8v*)((const unsigned short*)wb + j * 512 + l * 8);
}

// chunk staging: 15 chunks/step, 32 frags (32KB) each; 16 waves x 2 frags.
// C=0..12 identical to R15; C=13 = o3h plane (j = wn*8+kc), C=14 = o3l plane.
template <int C>
__device__ __forceinline__ void stage_chunk(unsigned int* dst, int w, int l) {
#pragma unroll
    for (int i = 0; i < 2; ++i) {
        const int j = w * 2 + i;
        int src;
        if constexpr (C == 0)
            src = 384 + ((j >> 4) * 48) + (((j >> 3) & 1) * 8) + (j & 7);
        else if constexpr (C == 1)
            src = 400 + ((j >> 4) * 48) + (((j >> 3) & 1) * 8) + (j & 7);
        else if constexpr (C == 2)
            src = 416 + ((j >> 4) * 48) + (((j >> 3) & 1) * 8) + (j & 7);
        else if constexpr (C == 3)
            src = (j & 15) * 2 + ((j >> 4) * 32);
        else if constexpr (C == 4)
            src = (j & 15) * 2 + 1 + ((j >> 4) * 32);
        else if constexpr (C >= 5 && C <= 12)
            src = 64 + ((j >> 4) * 128) + ((j & 15) * 8) + (C - 5);
        else if constexpr (C == 13)
            src = 320 + j;              // o3h, ldw index = wn*8+kc
        else
            src = 352 + j;              // o3l
        gld16(g_wb + (size_t)src * 512 + l * 8, dst + j * 256);
    }
}

// prep: swizzle W[K x N] f32 into B-frag order, split bf16 hi+lo — UNCHANGED
__global__ void prep_kernel(const float* __restrict__ W, int K, int N,
                            int hi_off, int lo_off) {
    const int l = threadIdx.x;
    const int kcN = K >> 5;
    const int nt = blockIdx.x / kcN;
    const int kc = blockIdx.x % kcN;
    const int col = nt * 16 + (l & 15);
    const int k0 = kc * 32 + ((l >> 4) << 3);
    const size_t base = ((size_t)(nt * kcN + kc) * 64 + l) * 8;
#pragma unroll
    for (int b = 0; b < 8; ++b) {
        float wv = W[(size_t)(k0 + b) * N + col];
        unsigned short h = f2b(wv);
        g_wb[hi_off + base + b] = h;
        g_wb[lo_off + base + b] = f2b(wv - b2f(h));
    }
}

#define SWAP_WB() do { unsigned int* _t = wc; wc = wn_; wn_ = _t; } while (0)

extern "C" __global__ void __launch_bounds__(NT)
ode_sac_kernel(const float* __restrict__ y0,
               const float* __restrict__ tarr,
               const float* __restrict__ noise,
               const float* __restrict__ ob1, const float* __restrict__ ob2,
               const float* __restrict__ ob3,
               const float* __restrict__ amb1, const float* __restrict__ amb2,
               const float* __restrict__ amb3,
               const float* __restrict__ asb1, const float* __restrict__ asb2,
               const float* __restrict__ asb3,
               float* __restrict__ out) {
    __shared__ __align__(16) unsigned int y_pk[RB * SYW];    //  8704 B
    __shared__ __align__(16) unsigned int h1_pk[RB * SHW];   // 33280 B
    __shared__ __align__(16) unsigned int h2_pk[RB * SHW];   // 33280 B
    __shared__ __align__(16) unsigned int wbA[8192];         // 32768 B
    __shared__ __align__(16) unsigned int wbB[8192];         // 32768 B
    unsigned int* a1m = h1_pk;                 // mean-chain L1 out
    unsigned int* a1s = h1_pk + RB * SYW;      // std-chain  L1 out
    unsigned int* a2m = h2_pk;
    unsigned int* a2s = h2_pk + RB * SYW;
    float* sdep_s = (float*)(h1_pk + 2 * RB * SYW);  // [32][68] f32, SP2->SP3
    float* f3b_s  = (float*)h1_pk;                   // [32][68] f32, SP14->SP15

    const int tid = threadIdx.x;
    const int w  = tid >> 6;       // 0..15
    const int l  = tid & 63;
    const int lm = l & 15;
    const int lg = l >> 4;
    const int hw = w >> 3;         // 0 = mean-group(A), 1 = std-group(B)
    const int w7 = w & 7;
    const int wm = w7 >> 2;        // narrow-layer row half
    const int wn = w7 & 3;         // narrow-layer col quadrant
    const int cB = w & 7;          // B1 col-pair
    const int row0 = blockIdx.x * RB;
    const int cN = wn * 16 + lm;

    const float dt = tarr[1] - tarr[0];

    // biases (head-dependent for the actor chain)
    const float b1  = hw ? asb1[cN] : amb1[cN];
    const float b2  = hw ? asb2[cN] : amb2[cN];
    const float b3a = hw ? asb3[cN] : amb3[cN];
    const float b_o3 = ob3[cN];              // used by A only
    const float b_o2 = ob2[w * 16 + lm];     // P4 col-tile = w
    float b_o1v[2];
#pragma unroll
    for (int i = 0; i < 2; ++i) b_o1v[i] = ob1[(2 * cB + i) * 16 + lm];

    unsigned int* a1dst = hw ? a1s : a1m;
    unsigned int* a2dst = hw ? a2s : a2m;

    // prologue: stage chunk0; A-waves init y + out[0]
    stage_chunk<0>(wbA, w, l);
    float ysr[4];
    if (hw == 0) {
#pragma unroll
        for (int r = 0; r < 4; ++r) {
            const int row = wm * 16 + lg * 4 + r;
            const float v = y0[(size_t)(row0 + row) * DD + cN];
            ysr[r] = v;
            y_pk[row * SYW + cN] = packsplit(v);
            __builtin_nontemporal_store(v, &out[(size_t)(row0 + row) * DD + cN]);
        }
    }
    __syncthreads();
    unsigned int* wc = wbA;
    unsigned int* wn_ = wbB;

    for (int t = 0; t < NSTEP; ++t) {
        float u[4], mean[4], ep[4];
        f4v accB[2], acc4[2], f3;

        // ===== SP0: L1 of own head (c0); stage c1 =====
        stage_chunk<1>(wn_, w, l);
        if (hw) {
#pragma unroll
            for (int r = 0; r < 4; ++r) {
                const int row = wm * 16 + lg * 4 + r;
                ep[r] = __builtin_nontemporal_load(
                    &noise[(size_t)t * NB * DD + (size_t)(row0 + row) * DD + cN]);
            }
        }
        {
            f4v a = splat4(b1);
            const int base = hw * 16;
#pragma unroll
            for (int kc = 0; kc < 2; ++kc) {
                s8v yh, yl;
                ldsPK(&y_pk[(wm * 16 + lm) * SYW + kc * 32 + lg * 8], &yh, &yl);
                MM3(a, yh, yl, ldw(wc, base + 2 * wn + kc, l),
                    ldw(wc, base + 8 + 2 * wn + kc, l));
            }
#pragma unroll
            for (int r = 0; r < 4; ++r) {
                const int row = wm * 16 + lg * 4 + r;
                a1dst[row * SYW + cN] = packsplit(fmaxf(a[r], 0.0f));
            }
        }
        __syncthreads(); SWAP_WB();

        // ===== SP1: L2 of own head (c1); stage c2 =====
        stage_chunk<2>(wn_, w, l);
        {
            f4v a = splat4(b2);
            const int base = hw * 16;
#pragma unroll
            for (int kc = 0; kc < 2; ++kc) {
                s8v ah, al;
                ldsPK(&a1dst[(wm * 16 + lm) * SYW + kc * 32 + lg * 8], &ah, &al);
                MM3(a, ah, al, ldw(wc, base + 2 * wn + kc, l),
                    ldw(wc, base + 8 + 2 * wn + kc, l));
            }
#pragma unroll
            for (int r = 0; r < 4; ++r) {
                const int row = wm * 16 + lg * 4 + r;
                a2dst[row * SYW + cN] = packsplit(fmaxf(a[r], 0.0f));
            }
        }
        __syncthreads(); SWAP_WB();

        // ===== SP2: L3 of own head (c2); B writes sd*eps; stage c3 =====
        stage_chunk<3>(wn_, w, l);
        {
            f4v a = splat4(b3a);
            const int base = hw * 16;
#pragma unroll
            for (int kc = 0; kc < 2; ++kc) {
                s8v ah, al;
                ldsPK(&a2dst[(wm * 16 + lm) * SYW + kc * 32 + lg * 8], &ah, &al);
                MM3(a, ah, al, ldw(wc, base + 2 * wn + kc, l),
                    ldw(wc, base + 8 + 2 * wn + kc, l));
            }
            if (hw) {
#pragma unroll
                for (int r = 0; r < 4; ++r) {
                    const int row = wm * 16 + lg * 4 + r;
                    const float ls = clean_f(a[r]);
                    sdep_s[row * 68 + cN] = fast_softplus(ls) * ep[r];
                }
            } else {
#pragma unroll
                for (int r = 0; r < 4; ++r) mean[r] = clean_f(fast_tanh(a[r]));
            }
        }
        __syncthreads(); SWAP_WB();

        // ===== SP3: B1 kc0 (c3); A computes u; stage c4 =====
        stage_chunk<4>(wn_, w, l);
        if (hw == 0) {
#pragma unroll
            for (int r = 0; r < 4; ++r) {
                const int row = wm * 16 + lg * 4 + r;
                u[r] = fast_tanh(mean[r] + sdep_s[row * 68 + cN]);
            }
        }
        {
#pragma unroll
            for (int i = 0; i < 2; ++i) accB[i] = splat4(b_o1v[i]);
            s8v yh, yl;
            ldsPK(&y_pk[(hw * 16 + lm) * SYW + lg * 8], &yh, &yl);
#pragma unroll
            for (int i = 0; i < 2; ++i) {
                const int nt = 2 * cB + i;
                MM3(accB[i], yh, yl, ldw(wc, nt, l), ldw(wc, 16 + nt, l));
            }
        }
        __syncthreads(); SWAP_WB();

        // ===== SP4: B1 kc1 + h1 store (c4); stage c5 =====
        stage_chunk<5>(wn_, w, l);
        {
            s8v yh, yl;
            ldsPK(&y_pk[(hw * 16 + lm) * SYW + 32 + lg * 8], &yh, &yl);
#pragma unroll
            for (int i = 0; i < 2; ++i) {
                const int nt = 2 * cB + i;
                MM3(accB[i], yh, yl, ldw(wc, nt, l), ldw(wc, 16 + nt, l));
            }
#pragma unroll
            for (int i = 0; i < 2; ++i)
#pragma unroll
                for (int r = 0; r < 4; ++r) {
                    const int row = hw * 16 + lg * 4 + r;
                    const int col = (2 * cB + i) * 16 + lm;
                    h1_pk[row * SHW + col] = packsplit(fast_tanh(accB[i][r]));
                }
        }
        __syncthreads(); SWAP_WB();

        // ===== SP5..SP12: P4, col-tile w, kc 0..7 (c5..c12) =====
        acc4[0] = splat4(b_o2);
        acc4[1] = splat4(b_o2);
#define P4_BODY(Q)                                                            \
        {                                                                     \
            const int k0 = (Q) * 32 + lg * 8;                                 \
            s8v a0h, a0l, a1h_, a1l_;                                         \
            ldsPK(&h1_pk[(lm) * SHW + k0], &a0h, &a0l);                       \
            ldsPK(&h1_pk[(16 + lm) * SHW + k0], &a1h_, &a1l_);                \
            const s8v bh = ldw(wc, w, l), bl = ldw(wc, 16 + w, l);            \
            MM3(acc4[0], a0h, a0l, bh, bl);                                   \
            MM3(acc4[1], a1h_, a1l_, bh, bl);                                 \
        }
        stage_chunk<6>(wn_, w, l);  P4_BODY(0) __syncthreads(); SWAP_WB();
        stage_chunk<7>(wn_, w, l);  P4_BODY(1) __syncthreads(); SWAP_WB();
        stage_chunk<8>(wn_, w, l);  P4_BODY(2) __syncthreads(); SWAP_WB();
        stage_chunk<9>(wn_, w, l);  P4_BODY(3) __syncthreads(); SWAP_WB();
        stage_chunk<10>(wn_, w, l); P4_BODY(4) __syncthreads(); SWAP_WB();
        stage_chunk<11>(wn_, w, l); P4_BODY(5) __syncthreads(); SWAP_WB();
        stage_chunk<12>(wn_, w, l); P4_BODY(6) __syncthreads(); SWAP_WB();
        stage_chunk<13>(wn_, w, l);
        P4_BODY(7)
        {
#pragma unroll
            for (int mt = 0; mt < 2; ++mt)
#pragma unroll
                for (int r = 0; r < 4; ++r) {
                    const int row = mt * 16 + lg * 4 + r;
                    const int col = w * 16 + lm;
                    h2_pk[row * SHW + col] = packsplit(fast_softplus(acc4[mt][r]));
                }
        }
        __syncthreads(); SWAP_WB();

        // ===== SP13: P5 h-plane, A-waves (c13 = o3h); stage c14 =====
        stage_chunk<14>(wn_, w, l);
        if (hw == 0) {
            f3 = splat4(b_o3);
#pragma unroll
            for (int kc = 0; kc < 8; ++kc) {
                s8v ah, al;
                ldsPK(&h2_pk[(wm * 16 + lm) * SHW + kc * 32 + lg * 8], &ah, &al);
                const s8v bh = ldw(wc, wn * 8 + kc, l);
                f3 = MFMA(ah, bh, f3);
                f3 = MFMA(al, bh, f3);
            }
        }
        __syncthreads(); SWAP_WB();

        // ===== SP14: P5 l-plane, B-waves (c14 = o3l) -> scratch; stage c0' =====
        stage_chunk<0>(wn_, w, l);
        if (hw) {
            f4v fb = {0.0f, 0.0f, 0.0f, 0.0f};
#pragma unroll
            for (int kc = 0; kc < 8; ++kc) {
                s8v ah, al;
                ldsPK(&h2_pk[(wm * 16 + lm) * SHW + kc * 32 + lg * 8], &ah, &al);
                fb = MFMA(ah, ldw(wc, wn * 8 + kc, l), fb);
            }
#pragma unroll
            for (int r = 0; r < 4; ++r)
                f3b_s[(wm * 16 + lg * 4 + r) * 68 + cN] = fb[r];
        }
        __syncthreads(); SWAP_WB();   // wc = c0' for next step

        // ===== SP15: finalize (A-waves); NO stage, NO swap =====
        if (hw == 0) {
#pragma unroll
            for (int r = 0; r < 4; ++r) {
                const int row = wm * 16 + lg * 4 + r;
                const float f = f3[r] + f3b_s[row * 68 + cN];
                const float yn = ysr[r] + (f - u[r]) * dt;
                ysr[r] = yn;
                y_pk[row * SYW + cN] = packsplit(yn);
                __builtin_nontemporal_store(yn,
                    &out[(size_t)(t + 1) * NB * DD + (size_t)(row0 + row) * DD + cN]);
            }
        }
        __syncthreads();
    }
}

extern "C" void kernel_launch(void* const* d_in, const int* in_sizes, int n_in,
                              void* d_out, int out_size, void* d_ws, size_t ws_size,
                              hipStream_t stream) {
    const float* y0    = (const float*)d_in[0];
    const float* tarr  = (const float*)d_in[1];
    const float* noise = (const float*)d_in[2];
    const float* oW1 = (const float*)d_in[3];  const float* ob1 = (const float*)d_in[4];
    const float* oW2 = (const float*)d_in[5];  const float* ob2 = (const float*)d_in[6];
    const float* oW3 = (const float*)d_in[7];  const float* ob3 = (const float*)d_in[8];
    const float* amW1 = (const float*)d_in[9];  const float* amb1 = (const float*)d_in[10];
    const float* amW2 = (const float*)d_in[11]; const float* amb2 = (const float*)d_in[12];
    const float* amW3 = (const float*)d_in[13]; const float* amb3 = (const float*)d_in[14];
    const float* asW1 = (const float*)d_in[15]; const float* asb1 = (const float*)d_in[16];
    const float* asW2 = (const float*)d_in[17]; const float* asb2 = (const float*)d_in[18];
    const float* asW3 = (const float*)d_in[19]; const float* asb3 = (const float*)d_in[20];
    float* out = (float*)d_out;

    hipLaunchKernelGGL(prep_kernel, dim3(16 * 2), dim3(64), 0, stream, oW1, 64, 256, O1H, O1L);
    hipLaunchKernelGGL(prep_kernel, dim3(16 * 8), dim3(64), 0, stream, oW2, 256, 256, O2H, O2L);
    hipLaunchKernelGGL(prep_kernel, dim3(4 * 8),  dim3(64), 0, stream, oW3, 256, 64, O3H, O3L);
    hipLaunchKernelGGL(prep_kernel, dim3(4 * 2),  dim3(64), 0, stream, amW1, 64, 64, AM1H, AM1L);
    hipLaunchKernelGGL(prep_kernel, dim3(4 * 2),  dim3(64), 0, stream, amW2, 64, 64, AM2H, AM2L);
    hipLaunchKernelGGL(prep_kernel, dim3(4 * 2),  dim3(64), 0, stream, amW3, 64, 64, AM3H, AM3L);
    hipLaunchKernelGGL(prep_kernel, dim3(4 * 2),  dim3(64), 0, stream, asW1, 64, 64, AS1H, AS1L);
    hipLaunchKernelGGL(prep_kernel, dim3(4 * 2),  dim3(64), 0, stream, asW2, 64, 64, AS2H, AS2L);
    hipLaunchKernelGGL(prep_kernel, dim3(4 * 2),  dim3(64), 0, stream, asW3, 64, 64, AS3H, AS3L);

    hipLaunchKernelGGL(ode_sac_kernel, dim3(NB / RB), dim3(NT), 0, stream,
                       y0, tarr, noise,
                       ob1, ob2, ob3, amb1, amb2, amb3, asb1, asb2, asb3,
                       out);
}

// Round 18
// 1565.781 us; speedup vs baseline: 1.8453x; 1.8453x over previous
//
#include <hip/hip_runtime.h>
#include <hip/hip_bf16.h>
#include <math.h>

#define NB 16384
#define DD 64
#define HH 256
#define NSTEP 63
#define RB 32          // rows per block -> grid 512
#define NT 512         // 8 waves

#define SYW 68         // u32 stride, packed 64-wide bufs (y, actor)
#define SHW 260        // u32 stride, packed 256-wide bufs (h1, h2)

// g_wb layout (ushort units)
#define O1H 0
#define O1L 16384
#define O2H 32768
#define O2L 98304
#define O3H 163840
#define O3L 180224
#define AM1H 196608
#define AM1L 200704
#define AM2H 204800
#define AM2L 208896
#define AM3H 212992
#define AM3L 217088
#define AS1H 221184
#define AS1L 225280
#define AS2H 229376
#define AS2L 233472
#define AS3H 237568
#define AS3L 241664
#define WB_SHORTS 245760

__device__ unsigned short g_wb[WB_SHORTS];   // cached device memory

typedef __attribute__((ext_vector_type(8))) short s8v;
typedef __attribute__((ext_vector_type(4))) float f4v;
typedef __attribute__((ext_vector_type(4))) unsigned int u4v;

#define MFMA(a, b, c) __builtin_amdgcn_mfma_f32_16x16x32_bf16((a), (b), (c), 0, 0, 0)
#define MM3(acc, ah, al, bh, bl)                                 \
    do {                                                         \
        acc = MFMA(ah, bh, acc);                                 \
        acc = MFMA(ah, bl, acc);                                 \
        acc = MFMA(al, bh, acc);                                 \
    } while (0)

__device__ __forceinline__ unsigned short f2b(float x) {
    return __builtin_bit_cast(unsigned short, (__bf16)x);
}
__device__ __forceinline__ float b2f(unsigned short u) {
    return __builtin_bit_cast(float, (unsigned int)u << 16);
}
__device__ __forceinline__ unsigned int packsplit(float x) {
    const unsigned int xb = __builtin_bit_cast(unsigned int, x);
    const unsigned int hb = xb & 0xFFFF0000u;
    const float lof = x - __builtin_bit_cast(float, hb);
    const unsigned int lb = __builtin_bit_cast(unsigned int, lof);
    return __builtin_amdgcn_perm(lb, hb, 0x07060302);
}
__device__ __forceinline__ float fast_tanh(float x) {
    float e = __expf(-2.0f * fabsf(x));
    float r = __fdividef(1.0f - e, 1.0f + e);
    return copysignf(r, x);
}
__device__ __forceinline__ float fast_softplus(float x) {
    return fmaxf(x, 0.0f) + __logf(1.0f + __expf(-fabsf(x)));
}
__device__ __forceinline__ float clean_f(float x) { return isfinite(x) ? x : 0.0f; }
__device__ __forceinline__ f4v splat4(float b) { f4v v = {b, b, b, b}; return v; }

__device__ __forceinline__ void ldsPK(const unsigned int* p, s8v* hi, s8v* lo) {
    const u4v q0 = *(const u4v*)p;
    const u4v q1 = *(const u4v*)(p + 4);
    union { unsigned int u[4]; s8v v; } H, L;
    H.u[0] = __builtin_amdgcn_perm(q0[1], q0[0], 0x05040100);
    L.u[0] = __builtin_amdgcn_perm(q0[1], q0[0], 0x07060302);
    H.u[1] = __builtin_amdgcn_perm(q0[3], q0[2], 0x05040100);
    L.u[1] = __builtin_amdgcn_perm(q0[3], q0[2], 0x07060302);
    H.u[2] = __builtin_amdgcn_perm(q1[1], q1[0], 0x05040100);
    L.u[2] = __builtin_amdgcn_perm(q1[1], q1[0], 0x07060302);
    H.u[3] = __builtin_amdgcn_perm(q1[3], q1[2], 0x05040100);
    L.u[3] = __builtin_amdgcn_perm(q1[3], q1[2], 0x07060302);
    *hi = H.v; *lo = L.v;
}

// async 16B/lane global->LDS (dst = uniform base + lane*16; zero VGPR data cost)
__device__ __forceinline__ void gld16(const unsigned short* g, unsigned int* l) {
    __builtin_amdgcn_global_load_lds(
        (const __attribute__((address_space(1))) void*)(g),
        (__attribute__((address_space(3))) void*)(l), 16, 0, 0);
}

// read fragment j from LDS weight buffer (lane-linear ds_read_b128)
__device__ __forceinline__ s8v ldw(const unsigned int* wb, int j, int l) {
    return *(const s8v*)((const unsigned short*)wb + j * 512 + l * 8);
}

// ---- chunk staging: 15 chunks/step, 32 frags (32KB) each; wave w stages j=4w..4w+3.
// Identical to R15 (the 1581 us configuration).
template <int C>
__device__ __forceinline__ void stage_chunk(unsigned int* dst, int w, int l) {
#pragma unroll
    for (int i = 0; i < 4; ++i) {
        const int j = w * 4 + i;
        int src;
        if constexpr (C == 0)
            src = 384 + ((j >> 4) * 48) + (((j >> 3) & 1) * 8) + (j & 7);
        else if constexpr (C == 1)
            src = 400 + ((j >> 4) * 48) + (((j >> 3) & 1) * 8) + (j & 7);
        else if constexpr (C == 2)
            src = 416 + ((j >> 4) * 48) + (((j >> 3) & 1) * 8) + (j & 7);
        else if constexpr (C == 3)
            src = (j & 15) * 2 + ((j >> 4) * 32);
        else if constexpr (C == 4)
            src = (j & 15) * 2 + 1 + ((j >> 4) * 32);
        else if constexpr (C >= 5 && C <= 12)
            src = 64 + ((j >> 4) * 128) + ((j & 15) * 8) + (C - 5);
        else if constexpr (C == 13)
            src = 320 + (((j >> 2) & 1) * 32) + ((j & 3) * 8) + (j >> 3);
        else
            src = 320 + (((j >> 2) & 1) * 32) + ((j & 3) * 8) + (j >> 3) + 4;
        gld16(g_wb + (size_t)src * 512 + l * 8, dst + j * 256);
    }
}

// ---- merged prep: ONE launch covers all 9 weight matrices (saves 8 graph nodes).
// Block ranges: [0,32) oW1 | [32,160) oW2 | [160,192) oW3 | [192,240) actor x6.
__global__ void prep_all_kernel(const float* __restrict__ oW1, const float* __restrict__ oW2,
                                const float* __restrict__ oW3,
                                const float* __restrict__ amW1, const float* __restrict__ amW2,
                                const float* __restrict__ amW3,
                                const float* __restrict__ asW1, const float* __restrict__ asW2,
                                const float* __restrict__ asW3) {
    const int b = blockIdx.x;
    const float* W;
    int K, N, hi_off, lo_off, rel;
    if (b < 32)        { W = oW1; K = 64;  N = 256; hi_off = O1H; lo_off = O1L; rel = b; }
    else if (b < 160)  { W = oW2; K = 256; N = 256; hi_off = O2H; lo_off = O2L; rel = b - 32; }
    else if (b < 192)  { W = oW3; K = 256; N = 64;  hi_off = O3H; lo_off = O3L; rel = b - 160; }
    else {
        const int a = (b - 192) >> 3;   // 0..5
        rel = (b - 192) & 7;
        K = 64; N = 64;
        switch (a) {
            case 0: W = amW1; hi_off = AM1H; lo_off = AM1L; break;
            case 1: W = amW2; hi_off = AM2H; lo_off = AM2L; break;
            case 2: W = amW3; hi_off = AM3H; lo_off = AM3L; break;
            case 3: W = asW1; hi_off = AS1H; lo_off = AS1L; break;
            case 4: W = asW2; hi_off = AS2H; lo_off = AS2L; break;
            default: W = asW3; hi_off = AS3H; lo_off = AS3L; break;
        }
    }
    const int l = threadIdx.x;            // 64
    const int kcN = K >> 5;
    const int nt = rel / kcN;
    const int kc = rel % kcN;
    const int col = nt * 16 + (l & 15);
    const int k0 = kc * 32 + ((l >> 4) << 3);
    const size_t base = ((size_t)(nt * kcN + kc) * 64 + l) * 8;
#pragma unroll
    for (int bb = 0; bb < 8; ++bb) {
        float wv = W[(size_t)(k0 + bb) * N + col];
        unsigned short h = f2b(wv);
        g_wb[hi_off + base + bb] = h;
        g_wb[lo_off + base + bb] = f2b(wv - b2f(h));
    }
}

#define SWAP_WB() do { unsigned int* _t = wc; wc = wn_; wn_ = _t; } while (0)

extern "C" __global__ void __launch_bounds__(NT)
ode_sac_kernel(const float* __restrict__ y0,
               const float* __restrict__ tarr,
               const float* __restrict__ noise,
               const float* __restrict__ ob1, const float* __restrict__ ob2,
               const float* __restrict__ ob3,
               const float* __restrict__ amb1, const float* __restrict__ amb2,
               const float* __restrict__ amb3,
               const float* __restrict__ asb1, const float* __restrict__ asb2,
               const float* __restrict__ asb3,
               float* __restrict__ out) {
    __shared__ __align__(16) unsigned int y_pk[RB * SYW];    //  8704 B
    __shared__ __align__(16) unsigned int h1_pk[RB * SHW];   // 33280 B
    __shared__ __align__(16) unsigned int h2_pk[RB * SHW];   // 33280 B
    __shared__ __align__(16) unsigned int wbA[8192];         // 32768 B weight buf A
    __shared__ __align__(16) unsigned int wbB[8192];         // 32768 B weight buf B
    unsigned int* a1m = h1_pk;
    unsigned int* a1s = h1_pk + RB * SYW;
    unsigned int* a2m = h2_pk;
    unsigned int* a2s = h2_pk + RB * SYW;

    const int tid = threadIdx.x;
    const int w  = tid >> 6;
    const int l  = tid & 63;
    const int lm = l & 15;
    const int lg = l >> 4;
    const int wm = w >> 2;
    const int wn = w & 3;
    const int row0 = blockIdx.x * RB;
    const int cN = wn * 16 + lm;

    const float dt = tarr[1] - tarr[0];

    // biases
    const float b_am1 = amb1[cN], b_am2 = amb2[cN], b_am3 = amb3[cN];
    const float b_as1 = asb1[cN], b_as2 = asb2[cN], b_as3 = asb3[cN];
    const float b_o3  = ob3[cN];
    const float b_o2a = ob2[(w * 2) * 16 + lm];
    const float b_o2b = ob2[(w * 2 + 1) * 16 + lm];
    float b_o1v[4];
#pragma unroll
    for (int nt = 0; nt < 4; ++nt) b_o1v[nt] = ob1[wn * 64 + nt * 16 + lm];

    // prologue: stage chunk0 + y0 init + out[0]
    stage_chunk<0>(wbA, w, l);
    float ysr[4];
#pragma unroll
    for (int r = 0; r < 4; ++r) {
        const int row = wm * 16 + lg * 4 + r;
        const float v = y0[(size_t)(row0 + row) * DD + cN];
        ysr[r] = v;
        y_pk[row * SYW + cN] = packsplit(v);
        __builtin_nontemporal_store(v, &out[(size_t)(row0 + row) * DD + cN]);
    }
    __syncthreads();
    unsigned int* wc = wbA;
    unsigned int* wn_ = wbB;

    for (int t = 0; t < NSTEP; ++t) {
        float u[4], ep[4];
        f4v accB[4];       // B1 accumulator (spans SP3-SP4)
        f4v acc4[2][2];    // P4 accumulator (spans SP5-SP12)
        f4v f3;            // P5 accumulator (spans SP13-SP14)

        // ================= SP0: P1 (chunk0) =================
        stage_chunk<1>(wn_, w, l);
#pragma unroll
        for (int r = 0; r < 4; ++r) {
            const int row = wm * 16 + lg * 4 + r;
            ep[r] = __builtin_nontemporal_load(
                &noise[(size_t)t * NB * DD + (size_t)(row0 + row) * DD + cN]);
        }
        {
            f4v am = splat4(b_am1), as_ = splat4(b_as1);
#pragma unroll
            for (int kc = 0; kc < 2; ++kc) {
                s8v yh, yl;
                ldsPK(&y_pk[(wm * 16 + lm) * SYW + kc * 32 + lg * 8], &yh, &yl);
                MM3(am, yh, yl, ldw(wc, 2 * wn + kc, l), ldw(wc, 8 + 2 * wn + kc, l));
                MM3(as_, yh, yl, ldw(wc, 16 + 2 * wn + kc, l), ldw(wc, 24 + 2 * wn + kc, l));
            }
#pragma unroll
            for (int r = 0; r < 4; ++r) {
                const int row = wm * 16 + lg * 4 + r;
                a1m[row * SYW + cN] = packsplit(fmaxf(am[r], 0.0f));
                a1s[row * SYW + cN] = packsplit(fmaxf(as_[r], 0.0f));
            }
        }
        __syncthreads(); SWAP_WB();

        // ================= SP1: P2 (chunk1) =================
        stage_chunk<2>(wn_, w, l);
        {
            f4v am = splat4(b_am2), as_ = splat4(b_as2);
#pragma unroll
            for (int kc = 0; kc < 2; ++kc) {
                const int k0 = kc * 32 + lg * 8;
                s8v mh, ml, sh, sl;
                ldsPK(&a1m[(wm * 16 + lm) * SYW + k0], &mh, &ml);
                ldsPK(&a1s[(wm * 16 + lm) * SYW + k0], &sh, &sl);
                MM3(am, mh, ml, ldw(wc, 2 * wn + kc, l), ldw(wc, 8 + 2 * wn + kc, l));
                MM3(as_, sh, sl, ldw(wc, 16 + 2 * wn + kc, l), ldw(wc, 24 + 2 * wn + kc, l));
            }
#pragma unroll
            for (int r = 0; r < 4; ++r) {
                const int row = wm * 16 + lg * 4 + r;
                a2m[row * SYW + cN] = packsplit(fmaxf(am[r], 0.0f));
                a2s[row * SYW + cN] = packsplit(fmaxf(as_[r], 0.0f));
            }
        }
        __syncthreads(); SWAP_WB();

        // ================= SP2: P3 actor -> u (chunk2) =================
        stage_chunk<3>(wn_, w, l);
        {
            f4v m3 = splat4(b_am3), s3 = splat4(b_as3);
#pragma unroll
            for (int kc = 0; kc < 2; ++kc) {
                const int k0 = kc * 32 + lg * 8;
                s8v mh, ml, sh, sl;
                ldsPK(&a2m[(wm * 16 + lm) * SYW + k0], &mh, &ml);
                ldsPK(&a2s[(wm * 16 + lm) * SYW + k0], &sh, &sl);
                MM3(m3, mh, ml, ldw(wc, 2 * wn + kc, l), ldw(wc, 8 + 2 * wn + kc, l));
                MM3(s3, sh, sl, ldw(wc, 16 + 2 * wn + kc, l), ldw(wc, 24 + 2 * wn + kc, l));
            }
#pragma unroll
            for (int r = 0; r < 4; ++r) {
                const float mean = clean_f(fast_tanh(m3[r]));
                const float ls   = clean_f(s3[r]);
                const float sd   = fast_softplus(ls);
                u[r] = fast_tanh(mean + sd * ep[r]);
            }
        }
        __syncthreads(); SWAP_WB();

        // ================= SP3: B1 kc0 (chunk3) =================
        stage_chunk<4>(wn_, w, l);
        {
#pragma unroll
            for (int nt = 0; nt < 4; ++nt) accB[nt] = splat4(b_o1v[nt]);
            s8v yh, yl;
            ldsPK(&y_pk[(wm * 16 + lm) * SYW + 0 * 32 + lg * 8], &yh, &yl);
#pragma unroll
            for (int nt = 0; nt < 4; ++nt)
                MM3(accB[nt], yh, yl, ldw(wc, 4 * wn + nt, l), ldw(wc, 16 + 4 * wn + nt, l));
        }
        __syncthreads(); SWAP_WB();

        // ================= SP4: B1 kc1 + h1 store (chunk4) =================
        stage_chunk<5>(wn_, w, l);
        {
            s8v yh, yl;
            ldsPK(&y_pk[(wm * 16 + lm) * SYW + 1 * 32 + lg * 8], &yh, &yl);
#pragma unroll
            for (int nt = 0; nt < 4; ++nt)
                MM3(accB[nt], yh, yl, ldw(wc, 4 * wn + nt, l), ldw(wc, 16 + 4 * wn + nt, l));
#pragma unroll
            for (int nt = 0; nt < 4; ++nt)
#pragma unroll
                for (int r = 0; r < 4; ++r) {
                    const int row = wm * 16 + lg * 4 + r;
                    const int col = wn * 64 + nt * 16 + lm;
                    h1_pk[row * SHW + col] = packsplit(fast_tanh(accB[nt][r]));
                }
        }
        __syncthreads(); SWAP_WB();

        // ================= SP5..SP12: P4 kc q=0..7 (chunks 5..12) =================
        acc4[0][0] = splat4(b_o2a); acc4[0][1] = splat4(b_o2b);
        acc4[1][0] = splat4(b_o2a); acc4[1][1] = splat4(b_o2b);
#define P4_BODY(Q)                                                            \
        {                                                                     \
            const int k0 = (Q) * 32 + lg * 8;                                 \
            s8v a0h, a0l, a1h_, a1l_;                                         \
            ldsPK(&h1_pk[(0 * 16 + lm) * SHW + k0], &a0h, &a0l);              \
            ldsPK(&h1_pk[(1 * 16 + lm) * SHW + k0], &a1h_, &a1l_);            \
            const s8v bh0 = ldw(wc, 2 * w, l),     bl0 = ldw(wc, 16 + 2 * w, l); \
            const s8v bh1 = ldw(wc, 2 * w + 1, l), bl1 = ldw(wc, 17 + 2 * w, l); \
            MM3(acc4[0][0], a0h, a0l, bh0, bl0);                              \
            MM3(acc4[0][1], a0h, a0l, bh1, bl1);                              \
            MM3(acc4[1][0], a1h_, a1l_, bh0, bl0);                            \
            MM3(acc4[1][1], a1h_, a1l_, bh1, bl1);                            \
        }
        stage_chunk<6>(wn_, w, l);  P4_BODY(0) __syncthreads(); SWAP_WB();
        stage_chunk<7>(wn_, w, l);  P4_BODY(1) __syncthreads(); SWAP_WB();
        stage_chunk<8>(wn_, w, l);  P4_BODY(2) __syncthreads(); SWAP_WB();
        stage_chunk<9>(wn_, w, l);  P4_BODY(3) __syncthreads(); SWAP_WB();
        stage_chunk<10>(wn_, w, l); P4_BODY(4) __syncthreads(); SWAP_WB();
        stage_chunk<11>(wn_, w, l); P4_BODY(5) __syncthreads(); SWAP_WB();
        stage_chunk<12>(wn_, w, l); P4_BODY(6) __syncthreads(); SWAP_WB();
        // SP12: last kc + softplus + h2 store (chunk12)
        stage_chunk<13>(wn_, w, l);
        P4_BODY(7)
        {
#pragma unroll
            for (int mt = 0; mt < 2; ++mt)
#pragma unroll
                for (int ct = 0; ct < 2; ++ct)
#pragma unroll
                    for (int r = 0; r < 4; ++r) {
                        const int row = mt * 16 + lg * 4 + r;
                        const int col = (w * 2 + ct) * 16 + lm;
                        h2_pk[row * SHW + col] = packsplit(fast_softplus(acc4[mt][ct][r]));
                    }
        }
        __syncthreads(); SWAP_WB();

        // ================= SP13: P5 kc0..3 (chunk13) =================
        stage_chunk<14>(wn_, w, l);
        f3 = splat4(b_o3);
#pragma unroll
        for (int kc = 0; kc < 4; ++kc) {
            s8v ah, al;
            ldsPK(&h2_pk[(wm * 16 + lm) * SHW + kc * 32 + lg * 8], &ah, &al);
            MM3(f3, ah, al, ldw(wc, kc * 8 + wn, l), ldw(wc, kc * 8 + 4 + wn, l));
        }
        __syncthreads(); SWAP_WB();

        // ================= SP14: P5 kc4..7 + y update + out (chunk14) =================
        stage_chunk<0>(wn_, w, l);   // next step's chunk0
#pragma unroll
        for (int kc = 4; kc < 8; ++kc) {
            s8v ah, al;
            ldsPK(&h2_pk[(wm * 16 + lm) * SHW + kc * 32 + lg * 8], &ah, &al);
            MM3(f3, ah, al, ldw(wc, (kc - 4) * 8 + wn, l), ldw(wc, (kc - 4) * 8 + 4 + wn, l));
        }
#pragma unroll
        for (int r = 0; r < 4; ++r) {
            const int row = wm * 16 + lg * 4 + r;
            const float yn = ysr[r] + (f3[r] - u[r]) * dt;
            ysr[r] = yn;
            y_pk[row * SYW + cN] = packsplit(yn);
            __builtin_nontemporal_store(yn,
                &out[(size_t)(t + 1) * NB * DD + (size_t)(row0 + row) * DD + cN]);
        }
        __syncthreads(); SWAP_WB();
    }
}

extern "C" void kernel_launch(void* const* d_in, const int* in_sizes, int n_in,
                              void* d_out, int out_size, void* d_ws, size_t ws_size,
                              hipStream_t stream) {
    const float* y0    = (const float*)d_in[0];
    const float* tarr  = (const float*)d_in[1];
    const float* noise = (const float*)d_in[2];
    const float* oW1 = (const float*)d_in[3];  const float* ob1 = (const float*)d_in[4];
    const float* oW2 = (const float*)d_in[5];  const float* ob2 = (const float*)d_in[6];
    const float* oW3 = (const float*)d_in[7];  const float* ob3 = (const float*)d_in[8];
    const float* amW1 = (const float*)d_in[9];  const float* amb1 = (const float*)d_in[10];
    const float* amW2 = (const float*)d_in[11]; const float* amb2 = (const float*)d_in[12];
    const float* amW3 = (const float*)d_in[13]; const float* amb3 = (const float*)d_in[14];
    const float* asW1 = (const float*)d_in[15]; const float* asb1 = (const float*)d_in[16];
    const float* asW2 = (const float*)d_in[17]; const float* asb2 = (const float*)d_in[18];
    const float* asW3 = (const float*)d_in[19]; const float* asb3 = (const float*)d_in[20];
    float* out = (float*)d_out;

    // single merged prep launch (240 blocks) — replaces 9 separate graph nodes
    hipLaunchKernelGGL(prep_all_kernel, dim3(240), dim3(64), 0, stream,
                       oW1, oW2, oW3, amW1, amW2, amW3, asW1, asW2, asW3);

    hipLaunchKernelGGL(ode_sac_kernel, dim3(NB / RB), dim3(NT), 0, stream,
                       y0, tarr, noise,
                       ob1, ob2, ob3, amb1, amb2, amb3, asb1, asb2, asb3,
                       out);
}